// Round 2
// baseline (679.068 us; speedup 1.0000x reference)
//
#include <hip/hip_runtime.h>

typedef unsigned int  u32;
typedef unsigned short u16;

#define S_TOT 131072L   // 32*64*64 spatial
#define GC 256
#define XC 128
#define IC 128

typedef short bf16x8 __attribute__((ext_vector_type(8)));   // 8 bf16 in 4 VGPRs
typedef float f32x4  __attribute__((ext_vector_type(4)));

static __device__ __forceinline__ float bfbits2f(u32 h) {
    union { u32 u; float f; } v; v.u = h << 16; return v.f;
}
static __device__ __forceinline__ u16 bits2bf(u32 u) {   // RNE f32 bits -> bf16
    return (u16)((u + 0x7fffu + ((u >> 16) & 1u)) >> 16);
}
static __device__ __forceinline__ u16 f2bf(float f) {
    union { float f; u32 u; } v; v.f = f;
    return bits2bf(v.u);
}

// ws float layout:
//   [0 .. 16383]       conv stats SUM  [(conv*256 + n*128 + i)*32 + bucket]
//   [16384 .. 32767]   conv stats SQ   same index + 16384
//   [32768 .. 32831]   psi SUM [n*32 + bucket]
//   [32832 .. 32895]   psi SQ  [n*32 + bucket]          (memset 32896 floats)
//   sc = ws + 32896 floats:
//     [0..511] scale[conv*256+n*128+i], [512..1023] shift, [1024+n] pscale, [1026+n] pshift
//   psi  f32[2][S_TOT]  at ws + 0x40000 bytes  (1 MB)
//   wgb  bf16[128*256]  at ws + 0x140000 bytes (64 KB)
//   wxb  bf16[128*128]  follows (32 KB)

// ---------------- P0: weights f32 -> bf16 ----------------
__global__ void k_prep(const float* __restrict__ Wg, const float* __restrict__ Wx,
                       u16* __restrict__ wgb, u16* __restrict__ wxb)
{
    int gid = blockIdx.x * 256 + threadIdx.x;
    if (gid < 32768) wgb[gid] = f2bf(Wg[gid]);
    else if (gid < 49152) wxb[gid - 32768] = f2bf(Wx[gid - 32768]);
}

// ---------------- P1: conv1x1 GEMM (bf16 MFMA) + fused row stats ----------------
// grid (1024 sblk, 2 n, 2 conv), block 256. Tile: 128 rows(i) x 128 cols(s), BK=64.
__global__ __launch_bounds__(256) void k_conv(
    const float* __restrict__ g, const float* __restrict__ x,
    const u16* __restrict__ wgb, const u16* __restrict__ wxb,
    u16* __restrict__ ysg, u16* __restrict__ ysx,
    float* __restrict__ stats)
{
    const int conv = blockIdx.z;
    const int n    = blockIdx.y;
    const int sblk = blockIdx.x;
    const int K    = conv ? XC : GC;
    const u16* W   = conv ? wxb : wgb;
    const float* src = conv ? (x + (long)n * XC * S_TOT) : (g + (long)n * GC * S_TOT);
    u16* dst       = (conv ? ysx : ysg) + (long)n * IC * S_TOT;

    // Bt[s_local][c_local] bf16, pitch 72 (144B): b128 reads effectively conflict-free.
    __shared__ u16 Bt[128][72];
    __shared__ float rsum[128], rsq[128];

    const int t = threadIdx.x;
    if (t < 128) { rsum[t] = 0.f; rsq[t] = 0.f; }

    const int w = t >> 6, l = t & 63;
    const int wr = w >> 1, wc = w & 1;        // 2x2 wave grid, 64x64 per wave
    const int l15 = l & 15, q = l >> 4;

    f32x4 acc[4][4];
    #pragma unroll
    for (int a = 0; a < 4; ++a)
        #pragma unroll
        for (int b = 0; b < 4; ++b) acc[a][b] = (f32x4){0.f, 0.f, 0.f, 0.f};

    const int k4  = t & 15;     // c-group of 4 rows
    const int so8 = t >> 4;     // s-octet
    const long scol = (long)sblk * 128;

    const int KIT = K >> 6;
    for (int kk = 0; kk < KIT; ++kk) {
        const int c0 = kk << 6;
        __syncthreads();
        {   // stage 64c x 128s f32 chunk, converting + transposing in registers
            const float* sp = src + (long)(c0 + k4 * 4) * S_TOT + scol + so8 * 8;
            u32 R[4][8];
            #pragma unroll
            for (int r = 0; r < 4; ++r) {
                uint4 lo = *(const uint4*)(sp + (long)r * S_TOT);
                uint4 hi = *(const uint4*)(sp + (long)r * S_TOT + 4);
                R[r][0] = lo.x; R[r][1] = lo.y; R[r][2] = lo.z; R[r][3] = lo.w;
                R[r][4] = hi.x; R[r][5] = hi.y; R[r][6] = hi.z; R[r][7] = hi.w;
            }
            #pragma unroll
            for (int m = 0; m < 8; ++m) {
                uint2 wv;
                wv.x = (u32)bits2bf(R[0][m]) | ((u32)bits2bf(R[1][m]) << 16);
                wv.y = (u32)bits2bf(R[2][m]) | ((u32)bits2bf(R[3][m]) << 16);
                *(uint2*)(&Bt[so8 * 8 + m][k4 * 4]) = wv;   // ds_write_b64
            }
        }
        __syncthreads();
        #pragma unroll
        for (int ks = 0; ks < 2; ++ks) {
            const int ck = c0 + ks * 32 + q * 8;
            bf16x8 af[4], bfr[4];
            #pragma unroll
            for (int mi = 0; mi < 4; ++mi)   // A direct from global (L1/L2-hot bf16 W copy)
                af[mi] = *(const bf16x8*)(W + (long)(wr * 64 + mi * 16 + l15) * K + ck);
            #pragma unroll
            for (int ni = 0; ni < 4; ++ni)   // ds_read_b128
                bfr[ni] = *(const bf16x8*)(&Bt[wc * 64 + ni * 16 + l15][ks * 32 + q * 8]);
            #pragma unroll
            for (int mi = 0; mi < 4; ++mi)
                #pragma unroll
                for (int ni = 0; ni < 4; ++ni)
                    acc[mi][ni] = __builtin_amdgcn_mfma_f32_16x16x32_bf16(
                        af[mi], bfr[ni], acc[mi][ni], 0, 0, 0);
        }
    }

    // epilogue: store ys (bf16); C/D layout col=l&15, row=q*4+reg
    {
        u16* dl = dst + (long)(wr * 64 + q * 4) * S_TOT + scol + wc * 64 + l15;
        #pragma unroll
        for (int mi = 0; mi < 4; ++mi)
            #pragma unroll
            for (int ni = 0; ni < 4; ++ni)
                #pragma unroll
                for (int r = 0; r < 4; ++r)
                    dl[(long)(mi * 16 + r) * S_TOT + ni * 16] = f2bf(acc[mi][ni][r]);
    }

    // fused row stats: sum & sumsq over this block's 128 s-cols
    #pragma unroll
    for (int mi = 0; mi < 4; ++mi)
        #pragma unroll
        for (int r = 0; r < 4; ++r) {
            float vs = 0.f, vq = 0.f;
            #pragma unroll
            for (int ni = 0; ni < 4; ++ni) {
                float v = acc[mi][ni][r];
                vs += v; vq += v * v;
            }
            #pragma unroll
            for (int off = 1; off < 16; off <<= 1) {
                vs += __shfl_xor(vs, off, 64);
                vq += __shfl_xor(vq, off, 64);
            }
            if (l15 == 0) {
                int row = wr * 64 + mi * 16 + q * 4 + r;
                atomicAdd(&rsum[row], vs);
                atomicAdd(&rsq[row], vq);
            }
        }
    __syncthreads();
    if (t < 128) {   // bucketed global atomics: 32 buckets, 32 blocks/bucket
        float* p = stats + (long)(conv * 256 + n * 128 + t) * 32 + (sblk & 31);
        atomicAdd(p, rsum[t]);
        atomicAdd(p + 16384, rsq[t]);
    }
}

// ---------------- P2: finalize IN stats -> per-channel scale/shift ----------------
__global__ void k_fin(const float* __restrict__ stats, float* __restrict__ sc,
                      const float* gg, const float* bg,
                      const float* gx, const float* bx)
{
    int id = blockIdx.x * 256 + threadIdx.x;
    if (id >= 512) return;
    int conv = id >> 8, i = id & 127;
    const float* base = stats + (long)id * 32;
    float s = 0.f, qq = 0.f;
    #pragma unroll
    for (int b = 0; b < 32; ++b) { s += base[b]; qq += base[16384 + b]; }
    const float inv = 1.f / (float)S_TOT;
    float mean = s * inv;
    float var  = qq * inv - mean * mean;
    float rstd = rsqrtf(var + 1e-5f);
    float gamma = conv ? gx[i] : gg[i];
    float beta  = conv ? bx[i] : bg[i];
    float scale = gamma * rstd;
    sc[id] = scale;
    sc[512 + id] = beta - mean * scale;
}

// ---------------- P3: psi = sum_i wp[i]*relu(norm(yg)+norm(yx)) + psi stats ----------------
// grid (256 sblk, 2 n), block 256, 2 s per thread.
__global__ __launch_bounds__(256) void k_psi(
    const u16* __restrict__ ysg, const u16* __restrict__ ysx,
    const float* __restrict__ wpf, const float* __restrict__ sc,
    float* __restrict__ psi, float* __restrict__ stats)
{
    const int n = blockIdx.y;
    const long s = ((long)blockIdx.x * 256 + threadIdx.x) * 2;
    const u16* pg = ysg + (long)n * 128 * S_TOT + s;
    const u16* px = ysx + (long)n * 128 * S_TOT + s;
    float acc0 = 0.f, acc1 = 0.f;
    #pragma unroll 8
    for (int i = 0; i < 128; ++i) {
        float sg = sc[n * 128 + i];
        float sx = sc[256 + n * 128 + i];
        float sh = sc[512 + n * 128 + i] + sc[768 + n * 128 + i];
        float wp = wpf[i];
        u32 vg = *(const u32*)(pg + (long)i * S_TOT);
        u32 vx = *(const u32*)(px + (long)i * S_TOT);
        float h0 = fmaf(bfbits2f(vg & 0xffffu), sg, fmaf(bfbits2f(vx & 0xffffu), sx, sh));
        float h1 = fmaf(bfbits2f(vg >> 16),    sg, fmaf(bfbits2f(vx >> 16),    sx, sh));
        h0 = fmaxf(h0, 0.f); h1 = fmaxf(h1, 0.f);
        acc0 = fmaf(h0, wp, acc0);
        acc1 = fmaf(h1, wp, acc1);
    }
    *(float2*)(psi + (long)n * S_TOT + s) = make_float2(acc0, acc1);

    // block-reduce psi sums for the psi instance-norm
    float ps = acc0 + acc1, pq = acc0 * acc0 + acc1 * acc1;
    #pragma unroll
    for (int off = 1; off < 64; off <<= 1) {
        ps += __shfl_xor(ps, off, 64);
        pq += __shfl_xor(pq, off, 64);
    }
    __shared__ float bs[4], bq[4];
    if ((threadIdx.x & 63) == 0) { bs[threadIdx.x >> 6] = ps; bq[threadIdx.x >> 6] = pq; }
    __syncthreads();
    if (threadIdx.x == 0) {
        float* p = stats + 32768 + n * 32 + (blockIdx.x & 31);
        atomicAdd(p, bs[0] + bs[1] + bs[2] + bs[3]);
        atomicAdd(p + 64, bq[0] + bq[1] + bq[2] + bq[3]);
    }
}

// ---------------- P4: finalize psi IN -> pscale/pshift ----------------
__global__ void k_pfin(const float* __restrict__ stats, float* __restrict__ sc,
                       const float* gp, const float* bp)
{
    int n = threadIdx.x;
    if (n < 2) {
        float s = 0.f, qq = 0.f;
        #pragma unroll
        for (int b = 0; b < 32; ++b) {
            s  += stats[32768 + n * 32 + b];
            qq += stats[32832 + n * 32 + b];
        }
        const float inv = 1.f / (float)S_TOT;
        float mean = s * inv;
        float var  = qq * inv - mean * mean;
        float rstd = rsqrtf(var + 1e-5f);
        float scale = gp[0] * rstd;
        sc[1024 + n] = scale;
        sc[1026 + n] = bp[0] - mean * scale;
    }
}

// ---------------- P5: out = x * sigmoid(psi*pscale+pshift) ----------------
__global__ __launch_bounds__(256) void k_apply(
    const float* __restrict__ x, const float* __restrict__ psi,
    const float* __restrict__ sc, float* __restrict__ out)
{
    const long idx = ((long)blockIdx.x * 256 + threadIdx.x) * 8;
    const int n = (int)(idx >> 24);           // 128*131072 = 2^24 elems per n
    const long s = idx & (S_TOT - 1);
    const float ps = sc[1024 + n], pf = sc[1026 + n];
    float4 x0 = *(const float4*)(x + idx);
    float4 x1 = *(const float4*)(x + idx + 4);
    float4 p0 = *(const float4*)(psi + (long)n * S_TOT + s);
    float4 p1 = *(const float4*)(psi + (long)n * S_TOT + s + 4);
    float xv[8] = {x0.x, x0.y, x0.z, x0.w, x1.x, x1.y, x1.z, x1.w};
    float pv[8] = {p0.x, p0.y, p0.z, p0.w, p1.x, p1.y, p1.z, p1.w};
    float ov[8];
    #pragma unroll
    for (int m = 0; m < 8; ++m) {
        float z = fmaf(pv[m], ps, pf);
        float a = 1.f / (1.f + __expf(-z));
        ov[m] = xv[m] * a;
    }
    *(float4*)(out + idx)     = make_float4(ov[0], ov[1], ov[2], ov[3]);
    *(float4*)(out + idx + 4) = make_float4(ov[4], ov[5], ov[6], ov[7]);
}

extern "C" void kernel_launch(void* const* d_in, const int* in_sizes, int n_in,
                              void* d_out, int out_size, void* d_ws, size_t ws_size,
                              hipStream_t stream)
{
    const float* g  = (const float*)d_in[0];
    const float* x  = (const float*)d_in[1];
    const float* Wg = (const float*)d_in[2];
    const float* Wx = (const float*)d_in[3];
    const float* Wp = (const float*)d_in[4];
    const float* gg = (const float*)d_in[5];
    const float* bg = (const float*)d_in[6];
    const float* gx = (const float*)d_in[7];
    const float* bx = (const float*)d_in[8];
    const float* gp = (const float*)d_in[9];
    const float* bp = (const float*)d_in[10];
    float* out = (float*)d_out;

    char* ws = (char*)d_ws;
    float* stats = (float*)ws;                       // 32896 floats, zeroed below
    float* sc    = stats + 32896;                    // 1028 floats
    float* psi   = (float*)(ws + 0x40000);           // [2][S] f32 = 1 MB
    u16*   wgb   = (u16*)(ws + 0x140000);            // 32768 bf16
    u16*   wxb   = wgb + 32768;                      // 16384 bf16

    // ys (bf16) lives inside d_out: dead storage until k_apply overwrites it.
    u16* ysg = (u16*)d_out;                          // [2][128][S] bf16 = 64 MiB
    u16* ysx = ysg + 33554432L;                      // 64 MiB (exactly fills d_out)

    hipMemsetAsync(stats, 0, 32896 * sizeof(float), stream);

    dim3 b(256);
    k_prep  <<<192,              b, 0, stream>>>(Wg, Wx, wgb, wxb);
    k_conv  <<<dim3(1024, 2, 2), b, 0, stream>>>(g, x, wgb, wxb, ysg, ysx, stats);
    k_fin   <<<dim3(2),          b, 0, stream>>>(stats, sc, gg, bg, gx, bx);
    k_psi   <<<dim3(256, 2),     b, 0, stream>>>(ysg, ysx, Wp, sc, psi, stats);
    k_pfin  <<<1, 64, 0, stream>>>(stats, sc, gp, bp);
    k_apply <<<16384, b, 0, stream>>>(x, psi, sc, out);
}